// Round 1
// baseline (383.799 us; speedup 1.0000x reference)
//
#include <hip/hip_runtime.h>
#include <math.h>

#define B_ 4
#define S_ 2048
#define E_ 1024
#define H_ 16
#define D_ 64
#define MTOT (B_*S_)

typedef _Float16 half8v __attribute__((ext_vector_type(8)));
typedef _Float16 half4v __attribute__((ext_vector_type(4)));
typedef float f32x4 __attribute__((ext_vector_type(4)));

typedef __attribute__((address_space(1))) const void gconst_void;
typedef __attribute__((address_space(3))) void lds_void;

#define MFMA16(a,b,c) __builtin_amdgcn_mfma_f32_16x16x32_f16((a),(b),(c),0,0,0)

// ---------------- fp32 -> fp16 convert ----------------
__global__ __launch_bounds__(256) void cvt_f32_f16(const float* __restrict__ in,
                                                   _Float16* __restrict__ out, int n) {
  int i = (blockIdx.x * 256 + threadIdx.x) * 4;
  if (i >= n) return;
  float4 v = *(const float4*)(in + i);
  half4v o;
  o[0] = (_Float16)v.x; o[1] = (_Float16)v.y; o[2] = (_Float16)v.z; o[3] = (_Float16)v.w;
  *(half4v*)(out + i) = o;
}

// ---------------- mask prep (format auto-detect) ----------------
__global__ __launch_bounds__(1024) void mask_prep(const unsigned char* __restrict__ mraw,
                                                  float* __restrict__ maskadd,
                                                  float* __restrict__ qmask) {
  __shared__ int flags[2];  // [0]: all u32 in {0,1} -> int32; [1]: all u32 in {0,0x3f800000} -> f32
  const int tid = threadIdx.x;
  if (tid < 2) flags[tid] = 1;
  __syncthreads();
  const unsigned int* w = (const unsigned int*)mraw;
  for (int i = tid; i < 2048; i += 1024) {  // first 8KiB - safe under every candidate layout
    unsigned int v = w[i];
    if (!(v == 0u || v == 1u)) flags[0] = 0;
    if (!(v == 0u || v == 0x3f800000u)) flags[1] = 0;
  }
  __syncthreads();
  const int is_i32 = flags[0], is_f32 = flags[1];
  for (int i = tid; i < B_ * S_; i += 1024) {
    int mv;
    if (is_i32)      mv = ((const int*)mraw)[i];
    else if (is_f32) mv = (((const unsigned int*)mraw)[i] != 0u);
    else             mv = (mraw[i] != 0);
    maskadd[i] = mv ? 0.0f : -1000000.0f;
    qmask[i]   = mv ? 1.0f : 0.0f;
  }
}

// ---------------- GEMM staging: 128 rows x 32 f16 cols -> LDS (linear) ----------------
__device__ __forceinline__ void stage128x32(const _Float16* __restrict__ g, int ld,
                                            _Float16* lds, int wid, int lane) {
#pragma unroll
  for (int j = 0; j < 2; ++j) {
    const int c = j * 256 + wid * 64 + lane;          // 16B chunk id, lane-ordered
    const _Float16* src = g + (size_t)(c >> 2) * ld + (c & 3) * 8;
    _Float16* dst = lds + (size_t)(j * 256 + wid * 64) * 8;  // wave-uniform base; HW adds lane*16B
    __builtin_amdgcn_global_load_lds((gconst_void*)src, (lds_void*)dst, 16, 0, 0);
  }
}

// ---------------- QKV projection GEMM ----------------
// y = x @ W.T + b ; z = blockIdx.z selects (Q,K,V). Q,K stored (B,H,S,D); V stored transposed (B,H,D,S).
__global__ __launch_bounds__(256) void qkv_gemm(
    const _Float16* __restrict__ xh,
    const _Float16* __restrict__ wq, const _Float16* __restrict__ wk, const _Float16* __restrict__ wv,
    const float* __restrict__ bq, const float* __restrict__ bkp, const float* __restrict__ bvp,
    _Float16* __restrict__ Qh, _Float16* __restrict__ Kh, _Float16* __restrict__ Vth) {
  __shared__ _Float16 As[128 * 32];
  __shared__ _Float16 Bs[128 * 32];
  const int tid = threadIdx.x, lane = tid & 63, wid = tid >> 6;
  const int g = lane >> 4, r16 = lane & 15;
  const int bm = blockIdx.x * 128, bn = blockIdx.y * 128;
  const int z = blockIdx.z;
  const _Float16* w = (z == 0) ? wq : (z == 1) ? wk : wv;
  const float* bias = (z == 0) ? bq : (z == 1) ? bkp : bvp;
  const int wr = wid >> 1, wc = wid & 1;
  f32x4 acc[4][4] = {};
  for (int k0 = 0; k0 < E_; k0 += 32) {
    stage128x32(xh + (size_t)bm * E_ + k0, E_, As, wid, lane);
    stage128x32(w + (size_t)bn * E_ + k0, E_, Bs, wid, lane);
    __syncthreads();
    half8v a[4], bf[4];
#pragma unroll
    for (int i = 0; i < 4; ++i) a[i] = *(const half8v*)&As[(wr * 64 + i * 16 + r16) * 32 + g * 8];
#pragma unroll
    for (int i = 0; i < 4; ++i) bf[i] = *(const half8v*)&Bs[(wc * 64 + i * 16 + r16) * 32 + g * 8];
#pragma unroll
    for (int i = 0; i < 4; ++i)
#pragma unroll
      for (int j = 0; j < 4; ++j) acc[i][j] = MFMA16(a[i], bf[j], acc[i][j]);
    __syncthreads();
  }
  // epilogue: C/D layout col=lane&15, row=(lane>>4)*4+reg
#pragma unroll
  for (int i = 0; i < 4; ++i) {
#pragma unroll
    for (int j = 0; j < 4; ++j) {
      const int gn = bn + wc * 64 + j * 16 + r16;
      const float bb = bias[gn];
      const int h = gn >> 6, d = gn & 63;
      const int gm0 = bm + wr * 64 + i * 16 + g * 4;
      const int bb_ = gm0 >> 11, s0 = gm0 & (S_ - 1);
      if (z == 2) {
        half4v v4;
#pragma unroll
        for (int ii = 0; ii < 4; ++ii) v4[ii] = (_Float16)(acc[i][j][ii] + bb);
        *(half4v*)&Vth[((size_t)(bb_ * H_ + h) * D_ + d) * S_ + s0] = v4;
      } else {
        _Float16* out = (z == 0) ? Qh : Kh;
#pragma unroll
        for (int ii = 0; ii < 4; ++ii)
          out[((size_t)(bb_ * H_ + h) * S_ + (s0 + ii)) * D_ + d] = (_Float16)(acc[i][j][ii] + bb);
      }
    }
  }
}

// ---------------- flash attention ----------------
// block: 128 q rows (4 independent waves x 32 rows). K/V read from global (L2-resident per head).
__global__ __launch_bounds__(256) void attn_kernel(
    const _Float16* __restrict__ Qh, const _Float16* __restrict__ Kh, const _Float16* __restrict__ Vth,
    const float* __restrict__ maskadd, _Float16* __restrict__ Oh) {
  __shared__ float smask[S_];          // 8KB
  __shared__ _Float16 Pl[4][32 * 64];  // 16KB, per-wave P buffer
  const int tid = threadIdx.x, lane = tid & 63, wid = tid >> 6;
  const int g = lane >> 4, r16 = lane & 15;
  const int b = blockIdx.z, h = blockIdx.y, q0 = blockIdx.x * 128;
  const size_t bh = (size_t)(b * H_ + h);
  const _Float16* Qb = Qh + bh * S_ * D_;
  const _Float16* Kb = Kh + bh * S_ * D_;
  const _Float16* Vb = Vth + bh * D_ * S_;
  for (int i = tid; i < S_; i += 256) smask[i] = maskadd[b * S_ + i];
  const int qw = q0 + wid * 32;
  half8v aq[2][2];
#pragma unroll
  for (int m = 0; m < 2; ++m)
#pragma unroll
    for (int ks = 0; ks < 2; ++ks)
      aq[m][ks] = *(const half8v*)&Qb[(size_t)(qw + 16 * m + r16) * D_ + 32 * ks + 8 * g];
  __syncthreads();
  float mrow[2][4], lrow[2][4];
  f32x4 oacc[2][4] = {};
#pragma unroll
  for (int m = 0; m < 2; ++m)
#pragma unroll
    for (int i = 0; i < 4; ++i) { mrow[m][i] = -1e30f; lrow[m][i] = 0.f; }
  _Float16* Pw = &Pl[wid][0];
  const int swz_r = (r16 >> 2) << 4;  // read swizzle: row=16m+r16 -> ((row>>2)&3)<<4
  for (int kb = 0; kb < S_; kb += 64) {
    f32x4 sc[2][4] = {};
#pragma unroll
    for (int ks = 0; ks < 2; ++ks) {
#pragma unroll
      for (int n = 0; n < 4; ++n) {
        half8v bkf = *(const half8v*)&Kb[(size_t)(kb + n * 16 + r16) * D_ + 32 * ks + 8 * g];
        sc[0][n] = MFMA16(aq[0][ks], bkf, sc[0][n]);
        sc[1][n] = MFMA16(aq[1][ks], bkf, sc[1][n]);
      }
    }
    float madd[4];
#pragma unroll
    for (int n = 0; n < 4; ++n) madd[n] = smask[kb + n * 16 + r16];
#pragma unroll
    for (int m = 0; m < 2; ++m)
#pragma unroll
      for (int n = 0; n < 4; ++n)
#pragma unroll
        for (int i = 0; i < 4; ++i) sc[m][n][i] = sc[m][n][i] * 0.125f + madd[n];
    // online softmax: row r = 16m + 4g + i lives in 16 lanes (same g), one col each
    float corr[2][4];
#pragma unroll
    for (int m = 0; m < 2; ++m)
#pragma unroll
      for (int i = 0; i < 4; ++i) {
        float mx = fmaxf(fmaxf(sc[m][0][i], sc[m][1][i]), fmaxf(sc[m][2][i], sc[m][3][i]));
#pragma unroll
        for (int off = 1; off < 16; off <<= 1) mx = fmaxf(mx, __shfl_xor(mx, off));
        float mn = fmaxf(mrow[m][i], mx);
        corr[m][i] = __expf(mrow[m][i] - mn);
        mrow[m][i] = mn;
      }
    float rsum[2][4] = {};
#pragma unroll
    for (int m = 0; m < 2; ++m)
#pragma unroll
      for (int n = 0; n < 4; ++n) {
        const int c_swz = 16 * (n ^ g) + r16;  // write swizzle: c ^ (((r>>2)&3)<<4), (r>>2)&3 == g
#pragma unroll
        for (int i = 0; i < 4; ++i) {
          float p = __expf(sc[m][n][i] - mrow[m][i]);
          rsum[m][i] += p;
          Pw[(16 * m + 4 * g + i) * 64 + c_swz] = (_Float16)p;
        }
      }
#pragma unroll
    for (int m = 0; m < 2; ++m)
#pragma unroll
      for (int i = 0; i < 4; ++i) {
        float v = rsum[m][i];
#pragma unroll
        for (int off = 1; off < 16; off <<= 1) v += __shfl_xor(v, off);
        lrow[m][i] = lrow[m][i] * corr[m][i] + v;
      }
#pragma unroll
    for (int m = 0; m < 2; ++m)
#pragma unroll
      for (int n = 0; n < 4; ++n)
#pragma unroll
        for (int i = 0; i < 4; ++i) oacc[m][n][i] *= corr[m][i];
    // same-wave LDS RAW: wait writes, fence compiler reordering
    asm volatile("s_waitcnt lgkmcnt(0)" ::: "memory");
#pragma unroll
    for (int ks = 0; ks < 2; ++ks) {
      half8v ap[2];
#pragma unroll
      for (int m = 0; m < 2; ++m) {
        const int k0 = (32 * ks + 8 * g) ^ swz_r;
        ap[m] = *(const half8v*)&Pw[(16 * m + r16) * 64 + k0];
      }
#pragma unroll
      for (int n = 0; n < 4; ++n) {
        half8v bv = *(const half8v*)&Vb[(size_t)(n * 16 + r16) * S_ + kb + 32 * ks + 8 * g];
        oacc[0][n] = MFMA16(ap[0], bv, oacc[0][n]);
        oacc[1][n] = MFMA16(ap[1], bv, oacc[1][n]);
      }
    }
  }
  // epilogue -> O (B,S,E) fp16
#pragma unroll
  for (int m = 0; m < 2; ++m) {
    float inv[4];
#pragma unroll
    for (int i = 0; i < 4; ++i) inv[i] = 1.0f / lrow[m][i];
#pragma unroll
    for (int n = 0; n < 4; ++n) {
      const int d = 16 * n + r16;
#pragma unroll
      for (int i = 0; i < 4; ++i) {
        const int s = qw + 16 * m + 4 * g + i;
        Oh[((size_t)(b * S_ + s)) * E_ + h * D_ + d] = (_Float16)(oacc[m][n][i] * inv[i]);
      }
    }
  }
}

// ---------------- output projection + abs(o*mask), fp32 out ----------------
__global__ __launch_bounds__(256) void oproj_gemm(
    const _Float16* __restrict__ Oh, const _Float16* __restrict__ wo, const float* __restrict__ bo,
    const float* __restrict__ qmask, float* __restrict__ out) {
  __shared__ _Float16 As[128 * 32];
  __shared__ _Float16 Bs[128 * 32];
  const int tid = threadIdx.x, lane = tid & 63, wid = tid >> 6;
  const int g = lane >> 4, r16 = lane & 15;
  const int bm = blockIdx.x * 128, bn = blockIdx.y * 128;
  const int wr = wid >> 1, wc = wid & 1;
  f32x4 acc[4][4] = {};
  for (int k0 = 0; k0 < E_; k0 += 32) {
    stage128x32(Oh + (size_t)bm * E_ + k0, E_, As, wid, lane);
    stage128x32(wo + (size_t)bn * E_ + k0, E_, Bs, wid, lane);
    __syncthreads();
    half8v a[4], bf[4];
#pragma unroll
    for (int i = 0; i < 4; ++i) a[i] = *(const half8v*)&As[(wr * 64 + i * 16 + r16) * 32 + g * 8];
#pragma unroll
    for (int i = 0; i < 4; ++i) bf[i] = *(const half8v*)&Bs[(wc * 64 + i * 16 + r16) * 32 + g * 8];
#pragma unroll
    for (int i = 0; i < 4; ++i)
#pragma unroll
      for (int j = 0; j < 4; ++j) acc[i][j] = MFMA16(a[i], bf[j], acc[i][j]);
    __syncthreads();
  }
#pragma unroll
  for (int i = 0; i < 4; ++i) {
#pragma unroll
    for (int j = 0; j < 4; ++j) {
      const int gn = bn + wc * 64 + j * 16 + r16;
      const float bb = bo[gn];
      const int gm0 = bm + wr * 64 + i * 16 + g * 4;
#pragma unroll
      for (int ii = 0; ii < 4; ++ii) {
        const int gm = gm0 + ii;
        const float y = acc[i][j][ii] + bb;
        out[(size_t)gm * E_ + gn] = fabsf(y * qmask[gm]);
      }
    }
  }
}

extern "C" void kernel_launch(void* const* d_in, const int* in_sizes, int n_in,
                              void* d_out, int out_size, void* d_ws, size_t ws_size,
                              hipStream_t stream) {
  const float* x = (const float*)d_in[0];
  const unsigned char* mask = (const unsigned char*)d_in[1];
  const float* WQ_w = (const float*)d_in[2];
  const float* WQ_b = (const float*)d_in[3];
  const float* WK_w = (const float*)d_in[4];
  const float* WK_b = (const float*)d_in[5];
  const float* WV_w = (const float*)d_in[6];
  const float* WV_b = (const float*)d_in[7];
  const float* WO_w = (const float*)d_in[8];
  const float* WO_b = (const float*)d_in[9];

  char* ws = (char*)d_ws;
  size_t off = 0;
  _Float16* xh  = (_Float16*)(ws + off); off += (size_t)MTOT * E_ * 2;  // 16MB; reused as O after attn
  _Float16* wqh = (_Float16*)(ws + off); off += (size_t)E_ * E_ * 2;
  _Float16* wkh = (_Float16*)(ws + off); off += (size_t)E_ * E_ * 2;
  _Float16* wvh = (_Float16*)(ws + off); off += (size_t)E_ * E_ * 2;
  _Float16* woh = (_Float16*)(ws + off); off += (size_t)E_ * E_ * 2;
  _Float16* Qh  = (_Float16*)(ws + off); off += (size_t)MTOT * E_ * 2;
  _Float16* Kh  = (_Float16*)(ws + off); off += (size_t)MTOT * E_ * 2;
  _Float16* Vth = (_Float16*)(ws + off); off += (size_t)MTOT * E_ * 2;
  float* maskaddf = (float*)(ws + off); off += (size_t)B_ * S_ * 4;
  float* qmaskf   = (float*)(ws + off); off += (size_t)B_ * S_ * 4;
  if (ws_size < off) return;  // insufficient scratch: fail loudly via validation, don't corrupt

  const int NX = MTOT * E_;   // 8388608
  const int NW = E_ * E_;     // 1048576
  cvt_f32_f16<<<dim3(NX / 4 / 256), dim3(256), 0, stream>>>(x, xh, NX);
  cvt_f32_f16<<<dim3(NW / 4 / 256), dim3(256), 0, stream>>>(WQ_w, wqh, NW);
  cvt_f32_f16<<<dim3(NW / 4 / 256), dim3(256), 0, stream>>>(WK_w, wkh, NW);
  cvt_f32_f16<<<dim3(NW / 4 / 256), dim3(256), 0, stream>>>(WV_w, wvh, NW);
  cvt_f32_f16<<<dim3(NW / 4 / 256), dim3(256), 0, stream>>>(WO_w, woh, NW);
  mask_prep<<<dim3(1), dim3(1024), 0, stream>>>(mask, maskaddf, qmaskf);
  qkv_gemm<<<dim3(MTOT / 128, E_ / 128, 3), dim3(256), 0, stream>>>(
      xh, wqh, wkh, wvh, WQ_b, WK_b, WV_b, Qh, Kh, Vth);
  attn_kernel<<<dim3(S_ / 128, H_, B_), dim3(256), 0, stream>>>(Qh, Kh, Vth, maskaddf, xh);
  oproj_gemm<<<dim3(MTOT / 128, E_ / 128), dim3(256), 0, stream>>>(xh, woh, WO_b, qmaskf, (float*)d_out);
}